// Round 10
// baseline (76.349 us; speedup 1.0000x reference)
//
#include <hip/hip_runtime.h>

#define B 8
#define T 2048
#define D 256
#define L 8
#define E 64
#define BT (B*T)

typedef _Float16 f16;
typedef f16 f16x8 __attribute__((ext_vector_type(8)));
typedef float f32x4 __attribute__((ext_vector_type(4)));

// workspace layout (float offsets)
#define OFF_I   0
#define OFF_F   (OFF_I  + B*L*T)            // fp32
#define OFF_WT  (OFF_F  + B*L*T)            // f16 16*E*D
#define OFF_VT  (OFF_WT + 16*E*D/2)         // f16 B*L*E*T
#define OFF_KT  (OFF_VT + B*L*E*T/2)
#define OFF_X16 (OFF_KT + B*L*E*T/2)        // f16 BT*D
#define OFF_OQ  (OFF_X16 + BT*D/2)          // fp32 64*128
#define OFF_CP  (OFF_OQ + 64*128)           // fp32 64*4*4160

// ---------------------------------------------------------------------------
// K1: prep.  bx<512: ifproj; 512..527: weight transpose; 528..2575: x->f16
//            (dedicated streaming blocks); 2576..2583: o/q proj at t=T-1.
// ---------------------------------------------------------------------------
__global__ __launch_bounds__(256) void k_prep_all(const float* __restrict__ x,
        const float* __restrict__ Wlin, const float* __restrict__ blin,
        const float* __restrict__ Wml, const float* __restrict__ bml,
        float* __restrict__ ibuf, float* __restrict__ fbuf,
        f16* __restrict__ Wt16, f16* __restrict__ x16,
        float* __restrict__ oqbuf) {
    __shared__ __align__(16) char smem[49920];
    int tid = threadIdx.x;
    int bx = blockIdx.x;
    if (bx < 512) {
        float (*xs)[260] = (float(*)[260])smem;            // 32 x 260
        float (*wsm)[260] = (float(*)[260])(smem + 33280); // 16 x 260
        int t0 = bx * 32;
        {
            int row = tid >> 3, q = tid & 7;
            const float* src = x + (size_t)(t0 + row) * D + q * 32;
            #pragma unroll
            for (int j = 0; j < 8; ++j) {
                float4 v = *(const float4*)(src + j * 4);
                *(float4*)&xs[row][q * 32 + j * 4] = v;
            }
        }
        {
            int row = tid >> 4, c0 = (tid & 15) * 16;
            const float* src = Wlin + row * D + c0;
            #pragma unroll
            for (int j = 0; j < 4; ++j) {
                float4 v = *(const float4*)(src + j * 4);
                *(float4*)&wsm[row][c0 + j * 4] = v;
            }
        }
        __syncthreads();
        int tl = tid >> 4, g = tid & 15;
        float acc0 = 0.f, acc1 = 0.f;
        for (int i = 0; i < D; ++i) {
            float wv = wsm[g][i];
            acc0 += xs[tl * 2 + 0][i] * wv;
            acc1 += xs[tl * 2 + 1][i] * wv;
        }
        float bias = blin[g];
        float acc[2] = {acc0 + bias, acc1 + bias};
        #pragma unroll
        for (int u = 0; u < 2; ++u) {
            int t = t0 + tl * 2 + u;
            int b = t >> 11, tt = t & 2047;
            if (g < 8) ibuf[(b * L + g) * T + tt] = acc[u];
            else       fbuf[(b * L + (g - 8)) * T + tt] = acc[u];
        }
    } else if (bx < 528) {
        float (*ts)[65] = (float(*)[65])smem;              // 64 x 65
        int vkrow = bx - 512;
        int wrow = 8 + vkrow;
        for (int dc = 0; dc < 4; ++dc) {
            int d0 = dc * 64;
            int r = tid >> 2, cq = (tid & 3) * 16;
            const float* src = Wml + ((size_t)wrow * D + d0 + r) * E + cq;
            #pragma unroll
            for (int j = 0; j < 16; j += 4) {
                float4 v = *(const float4*)(src + j);
                ts[r][cq + j] = v.x; ts[r][cq + j + 1] = v.y;
                ts[r][cq + j + 2] = v.z; ts[r][cq + j + 3] = v.w;
            }
            __syncthreads();
            int e = tid >> 2, dq = (tid & 3) * 16;
            f16* dst = Wt16 + ((size_t)vkrow * E + e) * D + d0 + dq;
            f16x8 o0, o1;
            #pragma unroll
            for (int j = 0; j < 8; ++j) {
                o0[j] = (f16)ts[dq + j][e];
                o1[j] = (f16)ts[dq + 8 + j][e];
            }
            *(f16x8*)dst = o0;
            *(f16x8*)(dst + 8) = o1;
            __syncthreads();
        }
    } else if (bx < 2576) {
        int i = ((bx - 528) * 256 + tid) * 8;
        float4 v0 = *(const float4*)(x + i);
        float4 v1 = *(const float4*)(x + i + 4);
        f16x8 o;
        o[0] = (f16)v0.x; o[1] = (f16)v0.y; o[2] = (f16)v0.z; o[3] = (f16)v0.w;
        o[4] = (f16)v1.x; o[5] = (f16)v1.y; o[6] = (f16)v1.z; o[7] = (f16)v1.w;
        *(f16x8*)(x16 + i) = o;
    } else {
        // o/q projection at t=T-1 for l = bx-2576, all b, both gates
        float (*x8)[256] = (float(*)[256])smem;
        int l = bx - 2576;
        {
            int bb = tid >> 5, c = (tid & 31) * 8;
            const float* src = x + ((size_t)(bb * T + (T - 1))) * D + c;
            float4 v0 = *(const float4*)src, v1 = *(const float4*)(src + 4);
            *(float4*)&x8[bb][c] = v0;
            *(float4*)&x8[bb][c + 4] = v1;
        }
        __syncthreads();
        #pragma unroll
        for (int r = 0; r < 4; ++r) {
            int idx = r * 256 + tid;
            int gate = idx >> 9, b = (idx >> 6) & 7, e = idx & 63;
            int row = gate ? (24 + l) : l;
            const float* gp = Wml + (size_t)row * D * E + e;
            float s = 0.f;
            for (int kk = 0; kk < D; ++kk) s += x8[b][kk] * gp[(size_t)kk * E];
            s += bml[row * E + e];
            oqbuf[(b * L + l) * 128 + gate * 64 + e] = s;
        }
    }
}

// ---------------------------------------------------------------------------
// K2: v,k projection via f16 MFMA.  Tile 128(M) x 512(N), BK=32, 512 thr.
// grid (BT/128, 2); by = h (0 -> v cols, 1 -> k cols).  Output (e,t).
// ---------------------------------------------------------------------------
__global__ __launch_bounds__(512) void k_vkproj3(const f16* __restrict__ x16,
        const f16* __restrict__ Wt16, const float* __restrict__ bml,
        f16* __restrict__ Vt, f16* __restrict__ Kt) {
    __shared__ __align__(16) char lds[40960];   // As 8KB | Bs 32KB
    int tid = threadIdx.x;
    int bx = blockIdx.x, h = blockIdx.y;
    int t0 = bx * 128;
    const f16* xa = x16 + (size_t)t0 * D;
    const f16* wb = Wt16 + (size_t)h * 8 * E * D;
    int wv = tid >> 6, lane = tid & 63;
    int wr = wv >> 2, wc = wv & 3;
    int q = lane >> 4, lr = lane & 15;
    int sa_t = tid >> 2, sa_q = tid & 3;
    f32x4 acc[4][8] = {};
    for (int ks = 0; ks < 8; ++ks) {
        int k0 = ks * 32;
        {
            f16x8 v = *(const f16x8*)(xa + (size_t)sa_t * D + k0 + sa_q * 8);
            int ba = sa_t * 64 + ((sa_q ^ ((sa_t >> 1) & 3)) << 4);
            *(f16x8*)(lds + ba) = v;
        }
        #pragma unroll
        for (int rr = 0; rr < 4; ++rr) {
            int r = rr * 128 + (tid >> 2);
            int c = tid & 3;
            f16x8 v = *(const f16x8*)(wb + (size_t)r * D + k0 + c * 8);
            int ba = 8192 + r * 64 + ((c ^ ((r >> 1) & 3)) << 4);
            *(f16x8*)(lds + ba) = v;
        }
        __syncthreads();
        f16x8 a[4], bf[8];
        #pragma unroll
        for (int m = 0; m < 4; ++m) {
            int t = wr * 64 + m * 16 + lr;
            int ba = t * 64 + ((q ^ ((t >> 1) & 3)) << 4);
            a[m] = *(const f16x8*)(lds + ba);
        }
        #pragma unroll
        for (int n = 0; n < 8; ++n) {
            int c = wc * 128 + n * 16 + lr;
            int ba = 8192 + c * 64 + ((q ^ ((c >> 1) & 3)) << 4);
            bf[n] = *(const f16x8*)(lds + ba);
        }
        #pragma unroll
        for (int m = 0; m < 4; ++m)
            #pragma unroll
            for (int n = 0; n < 8; ++n)
                acc[m][n] = __builtin_amdgcn_mfma_f32_16x16x32_f16(
                    a[m], bf[n], acc[m][n], 0, 0, 0);
        __syncthreads();
    }
    const float* bp = bml + (size_t)(8 + h * 8) * E;
    int b_g = t0 >> 11, tin = t0 & 2047;
    f16* obase = h ? Kt : Vt;
    for (int p = 0; p < 4; ++p) {
        if (wc == p) {
            #pragma unroll
            for (int n = 0; n < 8; ++n) {
                int cc = n * 16 + lr;
                float bias = bp[p * 128 + cc];
                int swz = (cc & 7) << 4;
                #pragma unroll
                for (int m = 0; m < 4; ++m) {
                    #pragma unroll
                    for (int r = 0; r < 4; r += 2) {
                        int t = wr * 64 + m * 16 + q * 4 + r;
                        union { f16 h2[2]; unsigned u; } pk;
                        pk.h2[0] = (f16)(acc[m][n][r] + bias);
                        pk.h2[1] = (f16)(acc[m][n][r + 1] + bias);
                        int ba = cc * 256 + ((t * 2) ^ swz);
                        *(unsigned*)(lds + ba) = pk.u;
                    }
                }
            }
        }
        __syncthreads();
        {
            int cc = tid >> 2, part = tid & 3;
            int cg2 = p * 128 + cc;
            int l = cg2 >> 6, e = cg2 & 63;
            f16* dst = obase + ((size_t)((b_g * L + l) * E + e)) * T + tin + part * 32;
            int swz = (cc & 7) << 4;
            #pragma unroll
            for (int jj = 0; jj < 4; ++jj) {
                int t = part * 32 + jj * 8;
                int ba = cc * 256 + ((t * 2) ^ swz);
                *(f16x8*)(dst + jj * 8) = *(const f16x8*)(lds + ba);
            }
        }
        __syncthreads();
    }
}

// ---------------------------------------------------------------------------
// K3: per-(bl,tc): shuffle-scan + weighted C-GEMM + partial write.
// grid (64, 4) x 256 threads.  No fences/atomics.
// ---------------------------------------------------------------------------
__global__ __launch_bounds__(256) void k_cgemm3(const f16* __restrict__ Vt,
        const f16* __restrict__ Kt, const float* __restrict__ ibuf,
        const float* __restrict__ fbuf, float* __restrict__ Cpart) {
    __shared__ __align__(16) char smem[17664];
    float* red  = (float*)smem;                // 16384 B
    float* redn = (float*)(smem + 16384);      // 256 B
    float* wtot = (float*)(smem + 16640);      // 16 B
    float* wmax = (float*)(smem + 16656);      // 16 B
    f16*   wlds = (f16*)(smem + 16672);        // 1024 B
    int tid = threadIdx.x;
    int bl = blockIdx.x, tc = blockIdx.y;
    int wv = tid >> 6, lane = tid & 63;
    // ---- scan via wave shuffles (3 barriers) ----
    {
        const float* fp = fbuf + bl * T + tid * 8;
        const float* ip = ibuf + bl * T + tid * 8;
        float4 fa = *(const float4*)fp;
        float4 fb = *(const float4*)(fp + 4);
        float4 ia = *(const float4*)ip;
        float4 ib = *(const float4*)(ip + 4);
        float f0[8] = {fa.x, fa.y, fa.z, fa.w, fb.x, fb.y, fb.z, fb.w};
        float iv[8] = {ia.x, ia.y, ia.z, ia.w, ib.x, ib.y, ib.z, ib.w};
        float ls[8]; float run = 0.f;
        #pragma unroll
        for (int r = 0; r < 8; ++r) { run += f0[r]; ls[r] = run; }
        float sc = run;
        #pragma unroll
        for (int s = 1; s < 64; s <<= 1) {
            float u = __shfl_up(sc, s, 64);
            if (lane >= s) sc += u;
        }
        if (lane == 63) wtot[wv] = sc;
        __syncthreads();
        float woff = 0.f;
        #pragma unroll
        for (int w2 = 0; w2 < 4; ++w2) if (w2 < wv) woff += wtot[w2];
        float off = woff + sc - run;
        float e[8]; float lmax = -1e30f;
        #pragma unroll
        for (int r = 0; r < 8; ++r) { e[r] = iv[r] - (off + ls[r]); lmax = fmaxf(lmax, e[r]); }
        #pragma unroll
        for (int s = 1; s < 64; s <<= 1) lmax = fmaxf(lmax, __shfl_xor(lmax, s, 64));
        if (lane == 0) wmax[wv] = lmax;
        __syncthreads();
        float M = fmaxf(fmaxf(fmaxf(wmax[0], wmax[1]), fmaxf(wmax[2], wmax[3])), 0.f);
        int tg = tid * 8;
        if ((tg >> 9) == tc) {
            f16x8 w8;
            #pragma unroll
            for (int r = 0; r < 8; ++r) w8[r] = (f16)__expf(e[r] - M);
            *(f16x8*)&wlds[tg & 511] = w8;
        }
        __syncthreads();
    }
    // ---- weighted GEMM ----
    const f16* vp = Vt + (size_t)bl * E * T;
    const f16* kp = Kt + (size_t)bl * E * T;
    f32x4 acc[5][4] = {};
    #pragma unroll
    for (int kc = 0; kc < 4; ++kc) {
        int lo = wv * 128 + kc * 32 + (lane >> 4) * 8;
        int tt = tc * 512 + lo;
        f16x8 wfrag = *(const f16x8*)&wlds[lo];
        f16x8 a[5], bf[4];
        #pragma unroll
        for (int m = 0; m < 4; ++m) {
            int i = m * 16 + (lane & 15);
            f16x8 v = *(const f16x8*)(vp + (size_t)i * T + tt);
            a[m] = v * wfrag;
        }
        a[4] = wfrag;
        #pragma unroll
        for (int nn = 0; nn < 4; ++nn) {
            int j = nn * 16 + (lane & 15);
            bf[nn] = *(const f16x8*)(kp + (size_t)j * T + tt);
        }
        #pragma unroll
        for (int m = 0; m < 5; ++m)
            #pragma unroll
            for (int nn = 0; nn < 4; ++nn)
                acc[m][nn] = __builtin_amdgcn_mfma_f32_16x16x32_f16(
                    a[m], bf[nn], acc[m][nn], 0, 0, 0);
    }
    // ---- 4-wave in-block reduction ----
    for (int rr = 0; rr < 4; ++rr) {
        if (wv == rr) {
            #pragma unroll
            for (int m = 0; m < 4; ++m)
                #pragma unroll
                for (int nn = 0; nn < 4; ++nn)
                    #pragma unroll
                    for (int r = 0; r < 4; ++r) {
                        int row = m * 16 + (lane >> 4) * 4 + r;
                        int col = nn * 16 + (lane & 15);
                        if (rr == 0) red[row * 64 + col] = acc[m][nn][r];
                        else         red[row * 64 + col] += acc[m][nn][r];
                    }
            if ((lane >> 4) == 0) {
                #pragma unroll
                for (int nn = 0; nn < 4; ++nn) {
                    int col = nn * 16 + (lane & 15);
                    if (rr == 0) redn[col] = acc[4][nn][0];
                    else         redn[col] += acc[4][nn][0];
                }
            }
        }
        __syncthreads();
    }
    float* cp = Cpart + ((size_t)bl * 4 + tc) * 4160;
    #pragma unroll
    for (int j = 0; j < 4; ++j) {
        int idx = tid * 16 + j * 4;
        *(float4*)(cp + idx) = *(const float4*)(red + idx);
    }
    if (tid < 64) cp[4096 + tid] = redn[tid];
}

// ---------------------------------------------------------------------------
// K4: slim final — reduce 4 partials, h from oqbuf, write h + C.
// ---------------------------------------------------------------------------
__global__ __launch_bounds__(256) void k_final(const float* __restrict__ Cpart,
        const float* __restrict__ oqbuf, float* __restrict__ out) {
    __shared__ float Cs[E * E];
    __shared__ float ns[E];
    int tid = threadIdx.x;
    int bl = blockIdx.x;
    const float* cp = Cpart + (size_t)bl * 4 * 4160;
    #pragma unroll
    for (int j = 0; j < 4; ++j) {
        int idx = tid * 16 + j * 4;
        float4 s = {0, 0, 0, 0};
        #pragma unroll
        for (int p = 0; p < 4; ++p) {
            float4 v = *(const float4*)(cp + p * 4160 + idx);
            s.x += v.x; s.y += v.y; s.z += v.z; s.w += v.w;
        }
        *(float4*)&Cs[idx] = s;
        *(float4*)(out + 4096 + (size_t)bl * 4096 + idx) = s;
    }
    if (tid < 64) {
        float s = 0.f;
        #pragma unroll
        for (int p = 0; p < 4; ++p) s += cp[p * 4160 + 4096 + tid];
        ns[tid] = s;
    }
    __syncthreads();
    if (tid < 64) {
        int j = tid;
        float hc = 0.f, nq = 0.f;
        const float* oq = oqbuf + bl * 128;
        for (int i2 = 0; i2 < E; ++i2) {
            float qv = oq[64 + i2];
            hc += Cs[i2 * 64 + j] * qv;
            nq += ns[i2] * qv;
        }
        float denom = fmaxf(nq, 1.0f);
        float sg = 1.0f / (1.0f + __expf(-oq[j]));
        out[bl * 64 + j] = sg * hc / denom;
    }
}

extern "C" void kernel_launch(void* const* d_in, const int* in_sizes, int n_in,
                              void* d_out, int out_size, void* d_ws, size_t ws_size,
                              hipStream_t stream) {
    const float* x    = (const float*)d_in[0];
    const float* Wml  = (const float*)d_in[1];
    const float* bml  = (const float*)d_in[2];
    const float* Wlin = (const float*)d_in[3];
    const float* blin = (const float*)d_in[4];
    float* out = (float*)d_out;
    float* ws = (float*)d_ws;
    float* ibuf  = ws + OFF_I;
    float* fbuf  = ws + OFF_F;
    f16*   Wt16  = (f16*)(ws + OFF_WT);
    f16*   Vt    = (f16*)(ws + OFF_VT);
    f16*   Kt    = (f16*)(ws + OFF_KT);
    f16*   x16   = (f16*)(ws + OFF_X16);
    float* oqbuf = ws + OFF_OQ;
    float* Cpart = ws + OFF_CP;

    k_prep_all<<<2584, 256, 0, stream>>>(x, Wlin, blin, Wml, bml,
                                         ibuf, fbuf, Wt16, x16, oqbuf);
    k_vkproj3<<<dim3(BT / 128, 2), 512, 0, stream>>>(x16, Wt16, bml, Vt, Kt);
    k_cgemm3<<<dim3(B * L, 4), 256, 0, stream>>>(Vt, Kt, ibuf, fbuf, Cpart);
    k_final<<<B * L, 256, 0, stream>>>(Cpart, oqbuf, out);
}

// Round 11
// 65.336 us; speedup vs baseline: 1.1686x; 1.1686x over previous
//
#include <hip/hip_runtime.h>

#define B 8
#define T 2048
#define D 256
#define L 8
#define E 64
#define BT (B*T)

typedef _Float16 f16;
typedef f16 f16x8 __attribute__((ext_vector_type(8)));
typedef float f32x4 __attribute__((ext_vector_type(4)));

// workspace layout (float offsets)
#define OFF_I   0
#define OFF_F   (OFF_I  + B*L*T)            // fp32
#define OFF_WT  (OFF_F  + B*L*T)            // f16 16*E*D
#define OFF_VT  (OFF_WT + 16*E*D/2)         // f16 B*L*E*T
#define OFF_KT  (OFF_VT + B*L*E*T/2)
#define OFF_CP  (OFF_KT + B*L*E*T/2)        // fp32 64*4*4160
#define OFF_X16 (OFF_CP + 64*4*4160)        // f16 BT*D

// ---------------------------------------------------------------------------
// K1: fused prep.  bx<512: i/f projection; 512..527: v/k weight transpose;
//     528..2575: x fp32->f16 conversion.
// ---------------------------------------------------------------------------
__global__ __launch_bounds__(256) void k_prep_all(const float* __restrict__ x,
        const float* __restrict__ Wlin, const float* __restrict__ blin,
        const float* __restrict__ Wml,
        float* __restrict__ ibuf, float* __restrict__ fbuf,
        f16* __restrict__ Wt16, f16* __restrict__ x16) {
    __shared__ __align__(16) char smem[49920];
    int tid = threadIdx.x;
    int bx = blockIdx.x;
    if (bx < 512) {
        float (*xs)[260] = (float(*)[260])smem;            // 32 x 260
        float (*wsm)[260] = (float(*)[260])(smem + 33280); // 16 x 260
        int t0 = bx * 32;
        {
            int row = tid >> 3, q = tid & 7;
            const float* src = x + (size_t)(t0 + row) * D + q * 32;
            #pragma unroll
            for (int j = 0; j < 8; ++j) {
                float4 v = *(const float4*)(src + j * 4);
                *(float4*)&xs[row][q * 32 + j * 4] = v;
            }
        }
        {
            int row = tid >> 4, c0 = (tid & 15) * 16;
            const float* src = Wlin + row * D + c0;
            #pragma unroll
            for (int j = 0; j < 4; ++j) {
                float4 v = *(const float4*)(src + j * 4);
                *(float4*)&wsm[row][c0 + j * 4] = v;
            }
        }
        __syncthreads();
        int tl = tid >> 4, g = tid & 15;
        float acc0 = 0.f, acc1 = 0.f;
        for (int i = 0; i < D; ++i) {
            float wv = wsm[g][i];
            acc0 += xs[tl * 2 + 0][i] * wv;
            acc1 += xs[tl * 2 + 1][i] * wv;
        }
        float bias = blin[g];
        float acc[2] = {acc0 + bias, acc1 + bias};
        #pragma unroll
        for (int u = 0; u < 2; ++u) {
            int t = t0 + tl * 2 + u;
            int b = t >> 11, tt = t & 2047;
            if (g < 8) ibuf[(b * L + g) * T + tt] = acc[u];
            else       fbuf[(b * L + (g - 8)) * T + tt] = acc[u];
        }
    } else if (bx < 528) {
        float (*ts)[65] = (float(*)[65])smem;              // 64 x 65
        int vkrow = bx - 512;
        int wrow = 8 + vkrow;
        for (int dc = 0; dc < 4; ++dc) {
            int d0 = dc * 64;
            int r = tid >> 2, cq = (tid & 3) * 16;
            const float* src = Wml + ((size_t)wrow * D + d0 + r) * E + cq;
            #pragma unroll
            for (int j = 0; j < 16; j += 4) {
                float4 v = *(const float4*)(src + j);
                ts[r][cq + j] = v.x; ts[r][cq + j + 1] = v.y;
                ts[r][cq + j + 2] = v.z; ts[r][cq + j + 3] = v.w;
            }
            __syncthreads();
            int e = tid >> 2, dq = (tid & 3) * 16;
            f16* dst = Wt16 + ((size_t)vkrow * E + e) * D + d0 + dq;
            f16x8 o0, o1;
            #pragma unroll
            for (int j = 0; j < 8; ++j) {
                o0[j] = (f16)ts[dq + j][e];
                o1[j] = (f16)ts[dq + 8 + j][e];
            }
            *(f16x8*)dst = o0;
            *(f16x8*)(dst + 8) = o1;
            __syncthreads();
        }
    } else {
        int i = ((bx - 528) * 256 + tid) * 8;
        float4 v0 = *(const float4*)(x + i);
        float4 v1 = *(const float4*)(x + i + 4);
        f16x8 o;
        o[0] = (f16)v0.x; o[1] = (f16)v0.y; o[2] = (f16)v0.z; o[3] = (f16)v0.w;
        o[4] = (f16)v1.x; o[5] = (f16)v1.y; o[6] = (f16)v1.z; o[7] = (f16)v1.w;
        *(f16x8*)(x16 + i) = o;
    }
}

// ---------------------------------------------------------------------------
// K2: v,k projection via f16 MFMA.  Tile 128(M) x 512(N), BK=32, 512 thr.
// grid (BT/128, 2); by = h (0 -> v cols, 1 -> k cols).  Output (e,t).
// ---------------------------------------------------------------------------
__global__ __launch_bounds__(512) void k_vkproj3(const f16* __restrict__ x16,
        const f16* __restrict__ Wt16, const float* __restrict__ bml,
        f16* __restrict__ Vt, f16* __restrict__ Kt) {
    __shared__ __align__(16) char lds[40960];   // As 8KB | Bs 32KB
    int tid = threadIdx.x;
    int bx = blockIdx.x, h = blockIdx.y;
    int t0 = bx * 128;
    const f16* xa = x16 + (size_t)t0 * D;
    const f16* wb = Wt16 + (size_t)h * 8 * E * D;
    int wv = tid >> 6, lane = tid & 63;
    int wr = wv >> 2, wc = wv & 3;
    int q = lane >> 4, lr = lane & 15;
    int sa_t = tid >> 2, sa_q = tid & 3;
    f32x4 acc[4][8] = {};
    for (int ks = 0; ks < 8; ++ks) {
        int k0 = ks * 32;
        {
            f16x8 v = *(const f16x8*)(xa + (size_t)sa_t * D + k0 + sa_q * 8);
            int ba = sa_t * 64 + ((sa_q ^ ((sa_t >> 1) & 3)) << 4);
            *(f16x8*)(lds + ba) = v;
        }
        #pragma unroll
        for (int rr = 0; rr < 4; ++rr) {
            int r = rr * 128 + (tid >> 2);
            int c = tid & 3;
            f16x8 v = *(const f16x8*)(wb + (size_t)r * D + k0 + c * 8);
            int ba = 8192 + r * 64 + ((c ^ ((r >> 1) & 3)) << 4);
            *(f16x8*)(lds + ba) = v;
        }
        __syncthreads();
        f16x8 a[4], bf[8];
        #pragma unroll
        for (int m = 0; m < 4; ++m) {
            int t = wr * 64 + m * 16 + lr;
            int ba = t * 64 + ((q ^ ((t >> 1) & 3)) << 4);
            a[m] = *(const f16x8*)(lds + ba);
        }
        #pragma unroll
        for (int n = 0; n < 8; ++n) {
            int c = wc * 128 + n * 16 + lr;
            int ba = 8192 + c * 64 + ((q ^ ((c >> 1) & 3)) << 4);
            bf[n] = *(const f16x8*)(lds + ba);
        }
        #pragma unroll
        for (int m = 0; m < 4; ++m)
            #pragma unroll
            for (int n = 0; n < 8; ++n)
                acc[m][n] = __builtin_amdgcn_mfma_f32_16x16x32_f16(
                    a[m], bf[n], acc[m][n], 0, 0, 0);
        __syncthreads();
    }
    // epilogue: bias + f16, transpose via 32KB LDS window (128 cols x 128 t)
    const float* bp = bml + (size_t)(8 + h * 8) * E;
    int b_g = t0 >> 11, tin = t0 & 2047;
    f16* obase = h ? Kt : Vt;
    for (int p = 0; p < 4; ++p) {
        if (wc == p) {
            #pragma unroll
            for (int n = 0; n < 8; ++n) {
                int cc = n * 16 + lr;          // 0..127 in window
                float bias = bp[p * 128 + cc];
                int swz = (cc & 7) << 4;
                #pragma unroll
                for (int m = 0; m < 4; ++m) {
                    #pragma unroll
                    for (int r = 0; r < 4; r += 2) {
                        int t = wr * 64 + m * 16 + q * 4 + r;
                        union { f16 h2[2]; unsigned u; } pk;
                        pk.h2[0] = (f16)(acc[m][n][r] + bias);
                        pk.h2[1] = (f16)(acc[m][n][r + 1] + bias);
                        int ba = cc * 256 + ((t * 2) ^ swz);
                        *(unsigned*)(lds + ba) = pk.u;
                    }
                }
            }
        }
        __syncthreads();
        {
            int cc = tid >> 2, part = tid & 3;
            int cg = p * 128 + cc;
            int l = cg >> 6, e = cg & 63;
            f16* dst = obase + ((size_t)((b_g * L + l) * E + e)) * T + tin + part * 32;
            int swz = (cc & 7) << 4;
            #pragma unroll
            for (int jj = 0; jj < 4; ++jj) {
                int t = part * 32 + jj * 8;
                int ba = cc * 256 + ((t * 2) ^ swz);
                *(f16x8*)(dst + jj * 8) = *(const f16x8*)(lds + ba);
            }
        }
        __syncthreads();
    }
}

// ---------------------------------------------------------------------------
// K3: C = sum_t w_t v_t k_t^T via MFMA, with INLINE scan (recomputed per
// block; identical fp order in all tc-blocks -> deterministic).
// grid (64, 4).  Row-64 trick gives n_j.  4 partials per bl.
// ---------------------------------------------------------------------------
__global__ __launch_bounds__(256) void k_cgemm2s(const f16* __restrict__ Vt,
        const f16* __restrict__ Kt, const float* __restrict__ ibuf,
        const float* __restrict__ fbuf, float* __restrict__ Cpart) {
    __shared__ float red[64 * 64];
    __shared__ float redn[64];
    __shared__ float part[256];
    __shared__ float rmax[256];
    __shared__ __align__(16) f16 wlds[512];
    int tid = threadIdx.x;
    int bl = blockIdx.x, tc = blockIdx.y;
    int wv = tid >> 6, lane = tid & 63;
    // ---- inline scan over full T for this bl ----
    {
        const float* fp = fbuf + bl * T + tid * 8;
        const float* ip = ibuf + bl * T + tid * 8;
        float4 fa = *(const float4*)fp;
        float4 fb = *(const float4*)(fp + 4);
        float4 ia = *(const float4*)ip;
        float4 ib = *(const float4*)(ip + 4);
        float f[8] = {fa.x, fa.y, fa.z, fa.w, fb.x, fb.y, fb.z, fb.w};
        float iv[8] = {ia.x, ia.y, ia.z, ia.w, ib.x, ib.y, ib.z, ib.w};
        float ls[8]; float run = 0.f;
        #pragma unroll
        for (int r = 0; r < 8; ++r) { run += f[r]; ls[r] = run; }
        part[tid] = run;
        __syncthreads();
        float inc = run;
        #pragma unroll
        for (int s = 1; s < 256; s <<= 1) {
            float u = (tid >= s) ? part[tid - s] : 0.f;
            __syncthreads();
            inc += u;
            part[tid] = inc;
            __syncthreads();
        }
        float off = inc - run;
        float e[8]; float lmax = -1e30f;
        #pragma unroll
        for (int r = 0; r < 8; ++r) { e[r] = iv[r] - (off + ls[r]); lmax = fmaxf(lmax, e[r]); }
        rmax[tid] = lmax;
        __syncthreads();
        for (int s = 128; s > 0; s >>= 1) {
            if (tid < s) rmax[tid] = fmaxf(rmax[tid], rmax[tid + s]);
            __syncthreads();
        }
        float M = fmaxf(rmax[0], 0.0f);
        int t = tid * 8;
        if ((t >> 9) == tc) {
            f16x8 w8;
            #pragma unroll
            for (int r = 0; r < 8; ++r) w8[r] = (f16)__expf(e[r] - M);
            *(f16x8*)&wlds[t & 511] = w8;
        }
        __syncthreads();
    }
    // ---- weighted C-GEMM ----
    const f16* vp = Vt + (size_t)bl * E * T;
    const f16* kp = Kt + (size_t)bl * E * T;
    f32x4 acc[5][4] = {};
    int tbase = tc * 512 + wv * 128;
    for (int kc = 0; kc < 4; ++kc) {
        int tt = tbase + kc * 32 + (lane >> 4) * 8;
        f16x8 wfrag = *(const f16x8*)&wlds[tt & 511];
        f16x8 a[5], bf[4];
        #pragma unroll
        for (int m = 0; m < 4; ++m) {
            int i = m * 16 + (lane & 15);
            f16x8 v = *(const f16x8*)(vp + (size_t)i * T + tt);
            a[m] = v * wfrag;
        }
        a[4] = wfrag;
        #pragma unroll
        for (int nn = 0; nn < 4; ++nn) {
            int j = nn * 16 + (lane & 15);
            bf[nn] = *(const f16x8*)(kp + (size_t)j * T + tt);
        }
        #pragma unroll
        for (int m = 0; m < 5; ++m)
            #pragma unroll
            for (int nn = 0; nn < 4; ++nn)
                acc[m][nn] = __builtin_amdgcn_mfma_f32_16x16x32_f16(
                    a[m], bf[nn], acc[m][nn], 0, 0, 0);
    }
    for (int rr = 0; rr < 4; ++rr) {
        if (wv == rr) {
            #pragma unroll
            for (int m = 0; m < 4; ++m)
                #pragma unroll
                for (int nn = 0; nn < 4; ++nn)
                    #pragma unroll
                    for (int r = 0; r < 4; ++r) {
                        int row = m * 16 + (lane >> 4) * 4 + r;
                        int col = nn * 16 + (lane & 15);
                        if (rr == 0) red[row * 64 + col] = acc[m][nn][r];
                        else         red[row * 64 + col] += acc[m][nn][r];
                    }
            if ((lane >> 4) == 0) {
                #pragma unroll
                for (int nn = 0; nn < 4; ++nn) {
                    int col = nn * 16 + (lane & 15);
                    if (rr == 0) redn[col] = acc[4][nn][0];
                    else         redn[col] += acc[4][nn][0];
                }
            }
        }
        __syncthreads();
    }
    float* cp = Cpart + ((size_t)bl * 4 + tc) * 4160;
    #pragma unroll
    for (int j = 0; j < 4; ++j) {
        int idx = tid * 16 + j * 4;
        *(float4*)(cp + idx) = *(const float4*)(red + idx);
    }
    if (tid < 64) cp[4096 + tid] = redn[tid];
}

// ---------------------------------------------------------------------------
// K4: reduce 4 partials, o/q at t=T-1, final h, write h + C.
// ---------------------------------------------------------------------------
__global__ __launch_bounds__(256) void k_final(const float* __restrict__ x,
        const float* __restrict__ Wml, const float* __restrict__ bml,
        const float* __restrict__ Cpart, float* __restrict__ out) {
    __shared__ float Cs[E * E];
    __shared__ float xs[D];
    __shared__ float ns[E];
    __shared__ float os[E];
    __shared__ float qs[E];
    int tid = threadIdx.x;
    int bl = blockIdx.x; int b = bl >> 3, l = bl & 7;
    xs[tid] = x[((size_t)(b * T + (T - 1))) * D + tid];
    const float* cp = Cpart + (size_t)bl * 4 * 4160;
    #pragma unroll
    for (int j = 0; j < 4; ++j) {
        int idx = tid * 16 + j * 4;
        float4 s = {0, 0, 0, 0};
        #pragma unroll
        for (int p = 0; p < 4; ++p) {
            float4 v = *(const float4*)(cp + p * 4160 + idx);
            s.x += v.x; s.y += v.y; s.z += v.z; s.w += v.w;
        }
        *(float4*)&Cs[idx] = s;
        *(float4*)(out + 4096 + (size_t)bl * (E * E) + idx) = s;
    }
    if (tid < 64) {
        float s = 0.f;
        #pragma unroll
        for (int p = 0; p < 4; ++p) s += cp[p * 4160 + 4096 + tid];
        ns[tid] = s;
    }
    __syncthreads();
    if (tid < 128) {
        int gate = tid >> 6, e = tid & 63;
        int wrow = gate ? (3 * L + l) : l;
        const float* wpp = Wml + (size_t)wrow * D * E + e;
        float s = 0.f;
        for (int kk = 0; kk < D; ++kk) s += xs[kk] * wpp[kk * E];
        s += bml[wrow * E + e];
        if (gate) qs[e] = s; else os[e] = s;
    }
    __syncthreads();
    if (tid < 64) {
        int j = tid;
        float hc = 0.f;
        for (int i2 = 0; i2 < E; ++i2) hc += Cs[i2 * E + j] * qs[i2];
        float nq = 0.f;
        for (int i2 = 0; i2 < E; ++i2) nq += ns[i2] * qs[i2];
        float denom = fmaxf(nq, 1.0f);
        float sg = 1.0f / (1.0f + __expf(-os[j]));
        out[bl * E + j] = sg * hc / denom;
    }
}

extern "C" void kernel_launch(void* const* d_in, const int* in_sizes, int n_in,
                              void* d_out, int out_size, void* d_ws, size_t ws_size,
                              hipStream_t stream) {
    const float* x    = (const float*)d_in[0];
    const float* Wml  = (const float*)d_in[1];
    const float* bml  = (const float*)d_in[2];
    const float* Wlin = (const float*)d_in[3];
    const float* blin = (const float*)d_in[4];
    float* out = (float*)d_out;
    float* ws = (float*)d_ws;
    float* ibuf  = ws + OFF_I;
    float* fbuf  = ws + OFF_F;
    f16*   Wt16  = (f16*)(ws + OFF_WT);
    f16*   Vt    = (f16*)(ws + OFF_VT);
    f16*   Kt    = (f16*)(ws + OFF_KT);
    float* Cpart = ws + OFF_CP;
    f16*   x16   = (f16*)(ws + OFF_X16);

    k_prep_all<<<2576, 256, 0, stream>>>(x, Wlin, blin, Wml, ibuf, fbuf, Wt16, x16);
    k_vkproj3<<<dim3(BT / 128, 2), 512, 0, stream>>>(x16, Wt16, bml, Vt, Kt);
    k_cgemm2s<<<dim3(B * L, 4), 256, 0, stream>>>(Vt, Kt, ibuf, fbuf, Cpart);
    k_final<<<B * L, 256, 0, stream>>>(x, Wml, bml, Cpart, out);
}